// Round 2
// baseline (941.922 us; speedup 1.0000x reference)
//
#include <hip/hip_runtime.h>

typedef _Float16 half8 __attribute__((ext_vector_type(8)));
typedef _Float16 half4 __attribute__((ext_vector_type(4)));
typedef float floatx4 __attribute__((ext_vector_type(4)));

#define NB 4        // batches per block
#define SX 136      // Xs/Gs row stride (fp16)
#define SVT 72      // Vt row stride
#define SP 72       // Ps row stride (Ps aliases the Gs buffer)

// Build W2: swizzled fp16 weight fragments, [ctg 0..23][ks 0..3][lane 0..63][i 0..7].
// ctg 0-7: Wqk = Wq.Wk^T (computed inline, fp32 dot), ctg 8-15: Wv, ctg 16-23: Wr.
// Element: W2[...] = M[ks*32 + q*8 + i][ctg16*16 + nn]  (M row = k/d index, col = output feature)
__global__ void wprep_kernel(const float* __restrict__ Wq, const float* __restrict__ Wk,
                             const float* __restrict__ Wv, const float* __restrict__ Wr,
                             _Float16* __restrict__ W2) {
    int idx  = blockIdx.x * 256 + threadIdx.x;   // 0 .. 49151
    int i    = idx & 7;
    int lane = (idx >> 3) & 63;
    int ks   = (idx >> 9) & 3;
    int ctg  = idx >> 11;                        // 0..23
    int q = lane >> 4, nn = lane & 15;
    int k = ks * 32 + q * 8 + i;                 // weight row (d index)
    float v;
    if (ctg < 8) {
        int e = ctg * 16 + nn;                   // Wqk[k][e] = dot(Wq row k, Wk row e)
        float s = 0.f;
        #pragma unroll 8
        for (int c = 0; c < 128; ++c) s += Wq[k * 128 + c] * Wk[e * 128 + c];
        v = s;
    } else if (ctg < 16) {
        v = Wv[k * 128 + (ctg - 8) * 16 + nn];
    } else {
        v = Wr[k * 128 + (ctg - 16) * 16 + nn];
    }
    W2[idx] = (_Float16)v;
}

__global__ __launch_bounds__(512, 6)
void autoint_kernel(const float* __restrict__ xg, const _Float16* __restrict__ W2,
                    float* __restrict__ outg) {
    const int tid  = threadIdx.x;
    const int w    = tid >> 6;        // wave 0..7
    const int lane = tid & 63;
    const int nn   = lane & 15;
    const int q    = lane >> 4;
    const int rb   = w & 3;           // score row-block (wave pairs w, w+4 duplicate QK)
    const long b0  = (long)blockIdx.x * NB;

    // 52 KB static LDS -> 3 blocks/CU
    __shared__ _Float16 lds[26624];
    _Float16* Xs = lds;               // 64 x 136 = 8704
    _Float16* Gs = lds + 8704;        // 64 x 136 = 8704 (G = X.Wqk)
    _Float16* Ps = Gs;                // 64 x 72 aliases Gs (disjoint lifetime across bar3)
    _Float16* Vt = lds + 17408;       // 128 x 72 = 9216 (V transposed [feature][key])

    // ---- weight fragments: wave w owns col-tile w of each of {Wqk, Wv, Wr} ----
    // c=0 -> G (ctg=w), c=1 -> V (ctg=8+w), c=2 -> R (ctg=16+w). 12 coalesced b128 loads.
    half8 wf[3][4];
    #pragma unroll
    for (int c = 0; c < 3; ++c) {
        int ctg = c * 8 + w;
        #pragma unroll
        for (int ks = 0; ks < 4; ++ks)
            wf[c][ks] = *(const half8*)(W2 + ((ctg * 4 + ks) * 64 + lane) * 8);
    }

    // ---- prologue: stage X(b0) (all 512 threads: 4 float4 each) ----
    float4 pf[4];
    {
        const float4* Xg = (const float4*)(xg + b0 * 8192);
        #pragma unroll
        for (int t = 0; t < 4; ++t) pf[t] = Xg[t * 512 + tid];
        #pragma unroll
        for (int t = 0; t < 4; ++t) {
            int g = t * 512 + tid;
            int row = g >> 5, c4 = (g & 31) * 4;
            half4 h = { (_Float16)pf[t].x, (_Float16)pf[t].y,
                        (_Float16)pf[t].z, (_Float16)pf[t].w };
            *(half4*)(Xs + row * SX + c4) = h;
        }
    }
    __syncthreads();   // bar1: Xs(b0) ready

    for (int it = 0; it < NB; ++it) {
        const long b = b0 + it;

        // prefetch next batch's X into registers (HBM latency hidden across phases)
        if (it + 1 < NB) {
            const float4* Xg = (const float4*)(xg + (b + 1) * 8192);
            #pragma unroll
            for (int t = 0; t < 4; ++t) pf[t] = Xg[t * 512 + tid];
        }

        // ---- P2: projections C(64x384) = X @ [Wqk|Wv|Wr], wave w owns one 16-col tile of each ----
        floatx4 acc[4][3];
        {
            floatx4 z = {0.f, 0.f, 0.f, 0.f};
            #pragma unroll
            for (int rt = 0; rt < 4; ++rt)
                #pragma unroll
                for (int c = 0; c < 3; ++c) acc[rt][c] = z;
        }
        #pragma unroll
        for (int ks = 0; ks < 4; ++ks) {
            half8 a[4];
            #pragma unroll
            for (int rt = 0; rt < 4; ++rt)
                a[rt] = *(const half8*)(Xs + (rt * 16 + nn) * SX + ks * 32 + q * 8);
            #pragma unroll
            for (int rt = 0; rt < 4; ++rt)
                #pragma unroll
                for (int c = 0; c < 3; ++c)
                    acc[rt][c] = __builtin_amdgcn_mfma_f32_16x16x32_f16(
                        a[rt], wf[c][ks], acc[rt][c], 0, 0, 0);
        }
        // scatter G -> Gs (row-major), V -> Vt (transposed). R stays in acc[rt][2].
        #pragma unroll
        for (int rt = 0; rt < 4; ++rt) {
            #pragma unroll
            for (int r = 0; r < 4; ++r)
                Gs[(rt * 16 + q * 4 + r) * SX + w * 16 + nn] = (_Float16)acc[rt][0][r];
            half4 hv = { (_Float16)acc[rt][1][0], (_Float16)acc[rt][1][1],
                         (_Float16)acc[rt][1][2], (_Float16)acc[rt][1][3] };
            *(half4*)(Vt + (w * 16 + nn) * SVT + rt * 16 + q * 4) = hv;
        }
        __syncthreads();   // bar2: Gs, Vt visible

        // ---- QK: S(row-block rb) = G Xt (duplicated across wave pairs; softmax wave-local) ----
        floatx4 sacc[4];
        {
            floatx4 z = {0.f, 0.f, 0.f, 0.f};
            #pragma unroll
            for (int ct = 0; ct < 4; ++ct) sacc[ct] = z;
        }
        #pragma unroll
        for (int ks = 0; ks < 4; ++ks) {
            half8 ag = *(const half8*)(Gs + (rb * 16 + nn) * SX + ks * 32 + q * 8);
            #pragma unroll
            for (int ct = 0; ct < 4; ++ct) {
                half8 bx = *(const half8*)(Xs + (ct * 16 + nn) * SX + ks * 32 + q * 8);
                sacc[ct] = __builtin_amdgcn_mfma_f32_16x16x32_f16(ag, bx, sacc[ct], 0, 0, 0);
            }
        }
        // softmax: row rb*16 + q*4 + r lives in the 16 lanes of quad q
        float pvals[4][2];                 // [r][local ct] -- this wave writes 2 of 4 col-tiles
        const int ct0 = (w >> 2) * 2;      // waves 0-3 -> cols 0..31, waves 4-7 -> cols 32..63
        #pragma unroll
        for (int r = 0; r < 4; ++r) {
            float mx = fmaxf(fmaxf(sacc[0][r], sacc[1][r]), fmaxf(sacc[2][r], sacc[3][r]));
            mx = fmaxf(mx, __shfl_xor(mx, 1));
            mx = fmaxf(mx, __shfl_xor(mx, 2));
            mx = fmaxf(mx, __shfl_xor(mx, 4));
            mx = fmaxf(mx, __shfl_xor(mx, 8));
            float e0 = __expf(sacc[0][r] - mx);
            float e1 = __expf(sacc[1][r] - mx);
            float e2 = __expf(sacc[2][r] - mx);
            float e3 = __expf(sacc[3][r] - mx);
            float s = e0 + e1 + e2 + e3;
            s += __shfl_xor(s, 1);
            s += __shfl_xor(s, 2);
            s += __shfl_xor(s, 4);
            s += __shfl_xor(s, 8);
            float inv = 1.0f / s;
            pvals[r][0] = ((ct0 == 0) ? e0 : e2) * inv;
            pvals[r][1] = ((ct0 == 0) ? e1 : e3) * inv;
        }
        __syncthreads();   // bar3: QK reads of Gs/Xs done -> safe to write Ps (alias Gs) and Xs(b+1)

        // P -> Ps (8 b16 stores), X(b+1) -> Xs
        #pragma unroll
        for (int r = 0; r < 4; ++r) {
            int row = rb * 16 + q * 4 + r;
            Ps[row * SP + (ct0 + 0) * 16 + nn] = (_Float16)pvals[r][0];
            Ps[row * SP + (ct0 + 1) * 16 + nn] = (_Float16)pvals[r][1];
        }
        if (it + 1 < NB) {
            #pragma unroll
            for (int t = 0; t < 4; ++t) {
                int g = t * 512 + tid;
                int row = g >> 5, c4 = (g & 31) * 4;
                half4 h = { (_Float16)pf[t].x, (_Float16)pf[t].y,
                            (_Float16)pf[t].z, (_Float16)pf[t].w };
                *(half4*)(Xs + row * SX + c4) = h;
            }
        }
        __syncthreads();   // bar4: Ps ready (Xs(b+1) also ready for next iter)

        // ---- PV: out col-tile w = P @ V[:, w*16..], fused relu(R + PV) ----
        floatx4 pv[4];
        {
            floatx4 z = {0.f, 0.f, 0.f, 0.f};
            #pragma unroll
            for (int rt = 0; rt < 4; ++rt) pv[rt] = z;
        }
        #pragma unroll
        for (int ks = 0; ks < 2; ++ks) {
            half8 bv = *(const half8*)(Vt + (w * 16 + nn) * SVT + ks * 32 + q * 8);
            #pragma unroll
            for (int rt = 0; rt < 4; ++rt) {
                half8 ap = *(const half8*)(Ps + (rt * 16 + nn) * SP + ks * 32 + q * 8);
                pv[rt] = __builtin_amdgcn_mfma_f32_16x16x32_f16(ap, bv, pv[rt], 0, 0, 0);
            }
        }
        float* ob = outg + b * 8192;
        #pragma unroll
        for (int rt = 0; rt < 4; ++rt)
            #pragma unroll
            for (int r = 0; r < 4; ++r) {
                int row = rt * 16 + q * 4 + r;
                float v = acc[rt][2][r] + pv[rt][r];
                ob[row * 128 + w * 16 + nn] = fmaxf(v, 0.0f);
            }
        __syncthreads();   // bar1: PV reads of Ps/Vt done -> next P2 may overwrite
    }
}

extern "C" void kernel_launch(void* const* d_in, const int* in_sizes, int n_in,
                              void* d_out, int out_size, void* d_ws, size_t ws_size,
                              hipStream_t stream) {
    const float* x  = (const float*)d_in[0];
    const float* Wq = (const float*)d_in[1];
    const float* Wk = (const float*)d_in[2];
    const float* Wv = (const float*)d_in[3];
    const float* Wr = (const float*)d_in[4];
    _Float16* W2 = (_Float16*)d_ws;      // 24*4*64*8 fp16 = 96 KB scratch
    float* out = (float*)d_out;

    wprep_kernel<<<192, 256, 0, stream>>>(Wq, Wk, Wv, Wr, W2);
    autoint_kernel<<<2048, 512, 0, stream>>>(x, W2, out);
}